// Round 10
// baseline (275.684 us; speedup 1.0000x reference)
//
#include <hip/hip_runtime.h>
#include <hip/hip_cooperative_groups.h>

#define NT    8192      // tokens (B*S)
#define DIM   1024      // d_model
#define NE    8         // experts
#define NH    512       // hidden
#define NROWS (NT*2)    // token-expert assignments (top_k=2)

typedef _Float16 f16;
typedef unsigned int u32;
typedef __attribute__((ext_vector_type(8))) _Float16 f16x8;
typedef __attribute__((ext_vector_type(4))) _Float16 f16x4;
typedef __attribute__((ext_vector_type(2))) _Float16 f16x2;
typedef __attribute__((ext_vector_type(4))) float f32x4;

// global -> LDS direct DMA, 16B per lane (wave-uniform base + lane*16).
__device__ __forceinline__ void gl2lds16(const f16* gptr, f16* ldsptr) {
    __builtin_amdgcn_global_load_lds(
        (const __attribute__((address_space(1))) u32*)gptr,
        (__attribute__((address_space(3))) u32*)ldsptr, 16, 0, 0);
}

// XOR-swizzled fragment read from unpadded [rows][32] f16 sub-tile
// (proven conflict-free: SQ_LDS_BANK_CONFLICT == 0).
#define FR(sbuf, row, q) \
    (*(const f16x8*)&sbuf[(row)*32 + (((q) ^ (((row) >> 1) & 3)) << 3)])

// ---------------- prep: router logits + x->f16 + weight transpose ----------
#define KC 512
__global__ __launch_bounds__(256) void prep_kernel(
    const float* __restrict__ x, const float* __restrict__ wr,
    const float* __restrict__ w1, const float* __restrict__ w3,
    const float* __restrict__ w2, float* __restrict__ plogits,
    f16* __restrict__ x16,
    f16* __restrict__ w1t, f16* __restrict__ w3t, f16* __restrict__ w2t,
    int* __restrict__ zint)
{
    __shared__ float smem[NE*KC];   // 16 KiB; transpose uses all 64*64 floats
    int tid = threadIdx.x;
    int bi = blockIdx.x;
    if (bi == 0 && tid < 16) zint[tid] = 0;   // ghist[8] | gcur[8]
    if (bi < 1024) {
        int bx = bi & 511, by = bi >> 9;
        int kc0 = by * KC;
        for (int i = tid; i < NE*KC; i += 256) {
            int k = i >> 3, e = i & 7;
            smem[e*KC + k] = wr[(size_t)kc0*NE + i];
        }
        __syncthreads();
        int tok = bx*16 + (tid >> 4);
        int kl  = tid & 15;
        float acc[NE];
        #pragma unroll
        for (int e = 0; e < NE; e++) acc[e] = 0.f;
        const float* xrow = x + (size_t)tok*DIM + kc0;
        f16* xhrow = x16 + (size_t)tok*DIM + kc0;
        #pragma unroll
        for (int i = 0; i < KC/64; i++) {
            int kb = i*64 + kl*4;
            float4 xv = *(const float4*)(xrow + kb);
            f16x4 xh = { (f16)xv.x, (f16)xv.y, (f16)xv.z, (f16)xv.w };
            *(f16x4*)(xhrow + kb) = xh;
            #pragma unroll
            for (int e = 0; e < NE; e++) {
                float4 wv = *(const float4*)&smem[e*KC + kb];
                acc[e] += xv.x*wv.x + xv.y*wv.y + xv.z*wv.z + xv.w*wv.w;
            }
        }
        #pragma unroll
        for (int e = 0; e < NE; e++) {
            float v = acc[e];
            v += __shfl_xor(v, 1); v += __shfl_xor(v, 2);
            v += __shfl_xor(v, 4); v += __shfl_xor(v, 8);
            acc[e] = v;
        }
        if (kl == 0) {
            float* pp = plogits + ((size_t)by*NT + tok)*NE;
            float4 o0 = {acc[0], acc[1], acc[2], acc[3]};
            float4 o1 = {acc[4], acc[5], acc[6], acc[7]};
            *(float4*)pp = o0;
            *(float4*)(pp + 4) = o1;
        }
    } else {
        int tz = bi - 1024;
        int zx = tz & 127, zy = tz >> 7;      // 128 64x64 tiles per (tensor,e)
        int tensor = zy >> 3, e = zy & 7;
        const float* src; f16* dst; int R, C;
        if (tensor == 0)      { src = w1; dst = w1t; R = DIM; C = NH; }
        else if (tensor == 1) { src = w3; dst = w3t; R = DIM; C = NH; }
        else                  { src = w2; dst = w2t; R = NH; C = DIM; }
        src += (size_t)e * DIM * NH;
        dst += (size_t)e * DIM * NH;
        int tcols = C >> 6;
        int bx = zx % tcols, by = zx / tcols;
        int r0 = by*64, c0 = bx*64;
        #pragma unroll
        for (int p = 0; p < 4; p++) {
            int r = p*16 + (tid >> 4);
            int c = (tid & 15) << 2;
            float4 v = *(const float4*)&src[(size_t)(r0 + r)*C + c0 + c];
            *(float4*)&smem[r*64 + (c ^ (((r >> 3) & 7) << 2))] = v;
        }
        __syncthreads();
        #pragma unroll
        for (int pass = 0; pass < 2; pass++) {
            int s = pass*256 + tid;
            int h = s >> 3, a = s & 7, d0 = a << 3;
            int hs = h ^ (a << 2);
            f16x8 o;
            #pragma unroll
            for (int j = 0; j < 8; j++)
                o[j] = (f16)smem[(d0 + j)*64 + hs];
            *(f16x8*)&dst[(size_t)(c0 + h)*R + r0 + d0] = o;
        }
    }
}

// ---------------- routescatter: fused route + ranked compaction -------------
// 64 cooperative blocks. Phase 1: threads 0..127 route 128 tokens/block
// (softmax+top2 -> LDS, global histogram). grid.sync(). Phase 2: all 256
// threads scatter this block's 256 assignments (same tokens -> LDS reuse).
// Row order within an expert is atomic-order-dependent, but every row is
// computed independently and scattered via aid, so out is order-invariant.
__global__ __launch_bounds__(256) void routescatter_kernel(
    const float* __restrict__ plogits, int* __restrict__ zint,
    int* __restrict__ offs, int* __restrict__ tok_ids,
    int* __restrict__ aid, float* __restrict__ row_gate)
{
    __shared__ unsigned char s_e[256];
    __shared__ float s_w[256];
    __shared__ int lhist[NE];
    int tid = threadIdx.x;
    int bi = blockIdx.x;
    if (tid < NE) lhist[tid] = 0;
    __syncthreads();

    if (tid < 128) {
        int t = bi*128 + tid;
        const float* p0 = plogits + (size_t)t*NE;
        const float* p1 = plogits + (size_t)NT*NE + (size_t)t*NE;
        float4 a0 = *(const float4*)p0, a1 = *(const float4*)(p0+4);
        float4 b0 = *(const float4*)p1, b1 = *(const float4*)(p1+4);
        float l[NE] = { a0.x+b0.x, a0.y+b0.y, a0.z+b0.z, a0.w+b0.w,
                        a1.x+b1.x, a1.y+b1.y, a1.z+b1.z, a1.w+b1.w };
        float m = l[0];
        #pragma unroll
        for (int e = 1; e < NE; e++) m = fmaxf(m, l[e]);
        float s = 0.f;
        #pragma unroll
        for (int e = 0; e < NE; e++) { l[e] = __expf(l[e] - m); s += l[e]; }
        float inv = 1.f / s;
        int i0 = 0; float v0 = l[0];
        #pragma unroll
        for (int e = 1; e < NE; e++) if (l[e] > v0) { v0 = l[e]; i0 = e; }
        int i1 = -1; float v1 = -1.f;
        #pragma unroll
        for (int e = 0; e < NE; e++) if (e != i0 && l[e] > v1) { v1 = l[e]; i1 = e; }
        s_e[2*tid+0] = (unsigned char)i0; s_w[2*tid+0] = v0*inv;
        s_e[2*tid+1] = (unsigned char)i1; s_w[2*tid+1] = v1*inv;
        #pragma unroll
        for (int ee = 0; ee < NE; ee++) {
            int c = __popcll(__ballot(i0 == ee)) + __popcll(__ballot(i1 == ee));
            if ((tid & 63) == 0 && c) atomicAdd(&lhist[ee], c);
        }
    }
    __syncthreads();
    if (tid < NE && lhist[tid]) atomicAdd(&zint[tid], lhist[tid]);   // ghist

    cooperative_groups::this_grid().sync();

    const int* ghist = zint;
    int* gcur = zint + 8;
    int loffs[NE]; int s = 0;
    #pragma unroll
    for (int e = 0; e < NE; e++) { loffs[e] = s; s += ghist[e]; }
    if (bi == 0 && tid == 0) {
        #pragma unroll
        for (int e = 0; e < NE; e++) offs[e] = loffs[e];
        offs[NE] = s;
    }
    int id = bi*256 + tid;
    int e = s_e[tid];
    float wv = s_w[tid];
    unsigned long long lt = (1ULL << (tid & 63)) - 1;
    int pos = 0;
    #pragma unroll
    for (int ee = 0; ee < NE; ee++) {
        unsigned long long mk = __ballot(e == ee);
        int cnt = __popcll(mk);
        int b = 0;
        if ((tid & 63) == 0 && cnt) b = atomicAdd(&gcur[ee], cnt);
        b = __shfl(b, 0);
        if (e == ee) pos = loffs[ee] + b + __popcll(mk & lt);
    }
    tok_ids[pos] = id >> 1;
    aid[pos] = id;
    row_gate[pos] = wv;
}

// ---------------- grouped GEMM tiles ----------------
// BK=64 as two 32-wide sub-tiles, full-drain schedule (proven best: R7).
// e = bi&7: expert == bi mod 8 == XCD under round-robin dispatch -> each
// XCD's L2 holds exactly one expert's weight panels (R6 post-mortem).
// launch_bounds(256,3): R9 showed (256,4) is a null lever — R7 config kept.

// GEMM1: BM=128 x BN=64 dual-B (w1 || w3). 256 B staged per MFMA.
#define BM1 128
#define BN1 64
__global__ __launch_bounds__(256,3) void gemm1_kernel(
    const f16* __restrict__ x16, const int* __restrict__ tok_ids,
    const f16* __restrict__ w1t, const f16* __restrict__ w3t,
    f16* __restrict__ gbuf, const int* __restrict__ offs)
{
    int bi = blockIdx.x;
    int e  = bi & 7;
    int r_ = bi >> 3;
    int nt = r_ & 7;          // NH/BN1 = 8
    int mt = r_ >> 3;
    int off = offs[e];
    int n_e = offs[e+1] - off;
    if (mt*BM1 >= n_e) return;

    __shared__ f16 sA [2][BM1*32];   // 16 KB
    __shared__ f16 sB1[2][BN1*32];   // 8 KB
    __shared__ f16 sB3[2][BN1*32];   // 8 KB
    __shared__ int stok[BM1];

    int tid = threadIdx.x;
    if (tid < BM1) {
        int rloc = mt*BM1 + tid; rloc = rloc < n_e ? rloc : n_e - 1;
        stok[tid] = tok_ids[off + rloc];
    }
    __syncthreads();

    int lane = tid & 63, w = tid >> 6;
    int wrow = (w >> 1)*64, wcol = (w & 1)*32;
    int q = lane >> 4, lm = lane & 15;

    // A staging (DMA, gathered): wave w covers rows [32w, 32w+32) in 2
    // chunks of 16 (proven conflict-free pattern).
    int lr0 = w*32 + (lane >> 2);
    int lr1 = lr0 + 16;
    int gA0 = (lane & 3) ^ ((lr0 >> 1) & 3);
    int gA1 = (lane & 3) ^ ((lr1 >> 1) & 3);
    const f16* pA0 = x16 + (size_t)stok[lr0]*DIM + gA0*8;
    const f16* pA1 = x16 + (size_t)stok[lr1]*DIM + gA1*8;
    const int lofs0 = lr0*32 + ((lane & 3) << 3);
    const int lofs1 = lr1*32 + ((lane & 3) << 3);

    // B staging (DMA): wave w covers rows [16w, 16w+16) of each B.
    int br = w*16 + (lane >> 2);
    int gB = (lane & 3) ^ ((br >> 1) & 3);
    const f16* w1p = w1t + ((size_t)e*NH + nt*BN1)*DIM;
    const f16* w3p = w3t + ((size_t)e*NH + nt*BN1)*DIM;
    const f16* pb1 = w1p + (size_t)br*DIM + gB*8;
    const f16* pb3 = w3p + (size_t)br*DIM + gB*8;
    const int bofs = br*32 + ((lane & 3) << 3);

    f32x4 acc1[4][2], acc3[4][2];
    #pragma unroll
    for (int a = 0; a < 4; a++)
        #pragma unroll
        for (int b = 0; b < 2; b++) {
            acc1[a][b] = (f32x4){0.f,0.f,0.f,0.f};
            acc3[a][b] = (f32x4){0.f,0.f,0.f,0.f};
        }

    for (int k0 = 0; k0 < DIM; k0 += 64) {
        __syncthreads();          // prev-tile FR reads complete
        gl2lds16(pA0 + k0,      &sA [0][lofs0]);
        gl2lds16(pA1 + k0,      &sA [0][lofs1]);
        gl2lds16(pA0 + k0 + 32, &sA [1][lofs0]);
        gl2lds16(pA1 + k0 + 32, &sA [1][lofs1]);
        gl2lds16(pb1 + k0,      &sB1[0][bofs]);
        gl2lds16(pb1 + k0 + 32, &sB1[1][bofs]);
        gl2lds16(pb3 + k0,      &sB3[0][bofs]);
        gl2lds16(pb3 + k0 + 32, &sB3[1][bofs]);
        __syncthreads();          // drains DMA
        #pragma unroll
        for (int ks = 0; ks < 2; ks++) {
            f16x8 aF[4], b1F[2], b3F[2];
            #pragma unroll
            for (int s = 0; s < 4; s++) aF[s] = FR(sA[ks], wrow + s*16 + lm, q);
            #pragma unroll
            for (int c = 0; c < 2; c++) {
                b1F[c] = FR(sB1[ks], wcol + c*16 + lm, q);
                b3F[c] = FR(sB3[ks], wcol + c*16 + lm, q);
            }
            #pragma unroll
            for (int sr = 0; sr < 4; sr++)
                #pragma unroll
                for (int sc = 0; sc < 2; sc++) {
                    acc1[sr][sc] = __builtin_amdgcn_mfma_f32_16x16x32_f16(aF[sr], b1F[sc], acc1[sr][sc], 0, 0, 0);
                    acc3[sr][sc] = __builtin_amdgcn_mfma_f32_16x16x32_f16(aF[sr], b3F[sc], acc3[sr][sc], 0, 0, 0);
                }
        }
    }
    // epilogue: silu(h1)*h3 -> f16 gbuf.  C/D: col=lane&15, row=(lane>>4)*4+reg
    #pragma unroll
    for (int sr = 0; sr < 4; sr++) {
        #pragma unroll
        for (int reg = 0; reg < 4; reg++) {
            int row = mt*BM1 + wrow + sr*16 + q*4 + reg;
            if (row < n_e) {
                #pragma unroll
                for (int sc = 0; sc < 2; sc++) {
                    int col = nt*BN1 + wcol + sc*16 + lm;
                    float h1 = acc1[sr][sc][reg];
                    float h3 = acc3[sr][sc][reg];
                    float gv = h1 / (1.f + __expf(-h1)) * h3;
                    gbuf[(size_t)(off + row)*NH + col] = (f16)gv;
                }
            }
        }
    }
}

// GEMM2: ybuf[aid[row]] = gate * (G @ W2). Full DMA staging, BK=64, 8 iters.
#define BM 128
#define BN 128
__global__ __launch_bounds__(256,3) void gemm2_kernel(
    const f16* __restrict__ gbuf, const f16* __restrict__ w2t,
    const int* __restrict__ offs, const int* __restrict__ aid,
    const float* __restrict__ row_gate, f16* __restrict__ ybuf)
{
    int bi = blockIdx.x;
    int e  = bi & 7;
    int r_ = bi >> 3;
    int nt = r_ & 7;          // DIM/BN = 8
    int mt = r_ >> 3;
    int off = offs[e];
    int n_e = offs[e+1] - off;
    if (mt*BM >= n_e) return;

    __shared__ f16 sA[2][BM*32];   // 16 KB
    __shared__ f16 sB[2][BN*32];   // 16 KB
    __shared__ int said[BM];
    __shared__ float sgate[BM];

    int tid = threadIdx.x;
    if (tid < BM) {
        int rloc = mt*BM + tid;
        if (rloc < n_e) { said[tid] = aid[off + rloc]; sgate[tid] = row_gate[off + rloc]; }
        else            { said[tid] = 0; sgate[tid] = 0.f; }
    }

    int lane = tid & 63, w = tid >> 6;
    int wrow = (w >> 1)*64, wcol = (w & 1)*64;
    int q = lane >> 4, lm = lane & 15;

    int lr0 = w*32 + (lane >> 2);
    int lr1 = lr0 + 16;
    int g0 = (lane & 3) ^ ((lr0 >> 1) & 3);
    int g1 = (lane & 3) ^ ((lr1 >> 1) & 3);
    int ga0 = mt*BM + lr0; ga0 = ga0 < n_e ? ga0 : n_e - 1;
    int ga1 = mt*BM + lr1; ga1 = ga1 < n_e ? ga1 : n_e - 1;
    const f16* pA0 = gbuf + (size_t)(off + ga0)*NH + g0*8;
    const f16* pA1 = gbuf + (size_t)(off + ga1)*NH + g1*8;
    const f16* w2p = w2t + ((size_t)e*DIM + nt*BN)*NH;
    const f16* pB0 = w2p + (size_t)lr0*NH + g0*8;
    const f16* pB1 = w2p + (size_t)lr1*NH + g1*8;
    const int lofs0 = lr0*32 + ((lane & 3) << 3);
    const int lofs1 = lr1*32 + ((lane & 3) << 3);

    f32x4 acc[4][4];
    #pragma unroll
    for (int a = 0; a < 4; a++)
        #pragma unroll
        for (int b = 0; b < 4; b++) acc[a][b] = (f32x4){0.f,0.f,0.f,0.f};

    __syncthreads();   // covers said/sgate writes

    for (int k0 = 0; k0 < NH; k0 += 64) {
        gl2lds16(pA0 + k0,      &sA[0][lofs0]);
        gl2lds16(pA1 + k0,      &sA[0][lofs1]);
        gl2lds16(pA0 + k0 + 32, &sA[1][lofs0]);
        gl2lds16(pA1 + k0 + 32, &sA[1][lofs1]);
        gl2lds16(pB0 + k0,      &sB[0][lofs0]);
        gl2lds16(pB1 + k0,      &sB[0][lofs1]);
        gl2lds16(pB0 + k0 + 32, &sB[1][lofs0]);
        gl2lds16(pB1 + k0 + 32, &sB[1][lofs1]);
        __syncthreads();   // drains vmcnt
        #pragma unroll
        for (int ks = 0; ks < 2; ks++) {
            f16x8 aF[4], bF[4];
            #pragma unroll
            for (int s = 0; s < 4; s++) {
                aF[s] = FR(sA[ks], wrow + s*16 + lm, q);
                bF[s] = FR(sB[ks], wcol + s*16 + lm, q);
            }
            #pragma unroll
            for (int sr = 0; sr < 4; sr++)
                #pragma unroll
                for (int sc = 0; sc < 4; sc++)
                    acc[sr][sc] = __builtin_amdgcn_mfma_f32_16x16x32_f16(aF[sr], bF[sc], acc[sr][sc], 0, 0, 0);
        }
        __syncthreads();   // reads done before next iter's DMA
    }
    #pragma unroll
    for (int sr = 0; sr < 4; sr++) {
        #pragma unroll
        for (int reg = 0; reg < 4; reg++) {
            int lrow = wrow + sr*16 + q*4 + reg;
            if (mt*BM + lrow < n_e) {
                int id = said[lrow];
                float wgt = sgate[lrow];
                #pragma unroll
                for (int sc = 0; sc < 4; sc++) {
                    int col = nt*BN + wcol + sc*16 + lm;
                    ybuf[(size_t)id*DIM + col] = (f16)(wgt * acc[sr][sc][reg]);
                }
            }
        }
    }
}

// ---------------- combine: out[t] = ybuf[2t] + ybuf[2t+1] ----------------
__global__ __launch_bounds__(256) void combine_kernel(
    const f16* __restrict__ ybuf, float* __restrict__ out)
{
    int gid = blockIdx.x*256 + threadIdx.x;
    int t = gid >> 7;
    int c = (gid & 127) << 3;
    f16x8 y0 = *(const f16x8*)(ybuf + ((size_t)2*t)*DIM + c);
    f16x8 y1 = *(const f16x8*)(ybuf + ((size_t)2*t+1)*DIM + c);
    float* op = out + (size_t)t*DIM + c;
    float4 o0 = { (float)y0[0] + (float)y1[0], (float)y0[1] + (float)y1[1],
                  (float)y0[2] + (float)y1[2], (float)y0[3] + (float)y1[3] };
    float4 o1 = { (float)y0[4] + (float)y1[4], (float)y0[5] + (float)y1[5],
                  (float)y0[6] + (float)y1[6], (float)y0[7] + (float)y1[7] };
    *(float4*)op = o0;
    *(float4*)(op + 4) = o1;
}

extern "C" void kernel_launch(void* const* d_in, const int* in_sizes, int n_in,
                              void* d_out, int out_size, void* d_ws, size_t ws_size,
                              hipStream_t stream)
{
    const float* x  = (const float*)d_in[0];
    const float* wr = (const float*)d_in[1];
    const float* w1 = (const float*)d_in[2];
    const float* w2 = (const float*)d_in[3];
    const float* w3 = (const float*)d_in[4];
    float* out = (float*)d_out;

    char* ws = (char*)d_ws;
    f16* ybuf    = (f16*)ws;        ws += (size_t)NROWS*DIM*sizeof(f16);   // 32 MiB (writer: gemm2)
    f16* w1t     = (f16*)ws;        ws += (size_t)NE*NH*DIM*sizeof(f16);   // 8 MiB (writer: prep)
    f16* w3t     = (f16*)ws;        ws += (size_t)NE*NH*DIM*sizeof(f16);   // 8 MiB (writer: prep)
    f16* w2t     = (f16*)ws;        ws += (size_t)NE*DIM*NH*sizeof(f16);   // 8 MiB (writer: prep)
    f16* gbuf    = (f16*)ws;        ws += (size_t)NROWS*NH*sizeof(f16);    // 16 MiB (writer: gemm1)
    float* plogits = (float*)ws;    ws += (size_t)2*NT*NE*4;               // 512 KiB (writer: prep)
    int* tok_ids = (int*)ws;        ws += (size_t)NROWS*4;                 // (writer: routescatter)
    int* aid     = (int*)ws;        ws += (size_t)NROWS*4;
    float* row_gate = (float*)ws;   ws += (size_t)NROWS*4;
    int* offs    = (int*)ws;        ws += 64;
    int* zint    = (int*)ws;        ws += 64;                              // ghist[8]|gcur[8]
    if (ws_size < (size_t)(ws - (char*)d_ws)) return;  // ~72.6 MB needed

    // x16 aliases ybuf: prep writes it, gemm1 reads it, then gemm2 overwrites
    // the region with ybuf (x16 dead by then). 16 MiB, zero workspace growth.
    f16* x16 = ybuf;

    prep_kernel<<<1024 + 3072, 256, 0, stream>>>(x, wr, w1, w3, w2,
                                                 plogits, x16, w1t, w3t, w2t, zint);
    {
        void* rsArgs[] = { (void*)&plogits, (void*)&zint, (void*)&offs,
                           (void*)&tok_ids, (void*)&aid, (void*)&row_gate };
        hipLaunchCooperativeKernel((void*)routescatter_kernel, dim3(64),
                                   dim3(256), rsArgs, 0, stream);
    }
    gemm1_kernel<<<4096, 256, 0, stream>>>(x16, tok_ids, w1t, w3t, gbuf, offs);
    gemm2_kernel<<<8192, 256, 0, stream>>>(gbuf, w2t, offs, aid, row_gate, ybuf);
    combine_kernel<<<(NT*(DIM/8))/256, 256, 0, stream>>>(ybuf, out);
}

// Round 11
// 221.020 us; speedup vs baseline: 1.2473x; 1.2473x over previous
//
#include <hip/hip_runtime.h>

#define NT    8192      // tokens (B*S)
#define DIM   1024      // d_model
#define NE    8         // experts
#define NH    512       // hidden
#define NROWS (NT*2)    // token-expert assignments (top_k=2)
#define RTB   512       // router blocks (16 tokens each)

typedef _Float16 f16;
typedef unsigned int u32;
typedef __attribute__((ext_vector_type(8))) _Float16 f16x8;
typedef __attribute__((ext_vector_type(4))) _Float16 f16x4;
typedef __attribute__((ext_vector_type(2))) _Float16 f16x2;
typedef __attribute__((ext_vector_type(4))) float f32x4;

// global -> LDS direct DMA, 16B per lane (wave-uniform base + lane*16).
__device__ __forceinline__ void gl2lds16(const f16* gptr, f16* ldsptr) {
    __builtin_amdgcn_global_load_lds(
        (const __attribute__((address_space(1))) u32*)gptr,
        (__attribute__((address_space(3))) u32*)ldsptr, 16, 0, 0);
}

// XOR-swizzled fragment read from unpadded [rows][32] f16 sub-tile
// (proven conflict-free: SQ_LDS_BANK_CONFLICT == 0).
#define FR(sbuf, row, q) \
    (*(const f16x8*)&sbuf[(row)*32 + (((q) ^ (((row) >> 1) & 3)) << 3)])

// ---------------- prep: full router (logits+softmax+top2+hist) + x->f16
//                        + weight transpose ----------------
// Router blocks 0..511: 16 tokens each, FULL K=1024 (route kernel fused in).
// Per-block histogram -> bhist[bi][e]; scatter derives exact prefix offsets
// deterministically (no global atomics, no zero-init needed).
__global__ __launch_bounds__(256) void prep_kernel(
    const float* __restrict__ x, const float* __restrict__ wr,
    const float* __restrict__ w1, const float* __restrict__ w3,
    const float* __restrict__ w2,
    f16* __restrict__ x16,
    f16* __restrict__ w1t, f16* __restrict__ w3t, f16* __restrict__ w2t,
    unsigned char* __restrict__ ge, float* __restrict__ gw,
    int* __restrict__ bhist)
{
    __shared__ float smem[NE*DIM];   // 32 KiB (router: wr panel; transpose: 16KB)
    __shared__ int lhist[NE];
    int tid = threadIdx.x;
    int bi = blockIdx.x;
    if (bi < RTB) {
        if (tid < NE) lhist[tid] = 0;
        for (int i = tid; i < NE*DIM; i += 256) {
            int k = i >> 3, e = i & 7;
            smem[e*DIM + k] = wr[i];      // wr[k][e] -> smem[e][k]
        }
        __syncthreads();
        int tok = bi*16 + (tid >> 4);
        int kl  = tid & 15;
        float acc[NE];
        #pragma unroll
        for (int e = 0; e < NE; e++) acc[e] = 0.f;
        const float* xrow = x + (size_t)tok*DIM;
        f16* xhrow = x16 + (size_t)tok*DIM;
        #pragma unroll
        for (int i = 0; i < DIM/64; i++) {
            int kb = i*64 + kl*4;
            float4 xv = *(const float4*)(xrow + kb);
            f16x4 xh = { (f16)xv.x, (f16)xv.y, (f16)xv.z, (f16)xv.w };
            *(f16x4*)(xhrow + kb) = xh;
            #pragma unroll
            for (int e = 0; e < NE; e++) {
                float4 wv = *(const float4*)&smem[e*DIM + kb];
                acc[e] += xv.x*wv.x + xv.y*wv.y + xv.z*wv.z + xv.w*wv.w;
            }
        }
        #pragma unroll
        for (int e = 0; e < NE; e++) {
            float v = acc[e];
            v += __shfl_xor(v, 1); v += __shfl_xor(v, 2);
            v += __shfl_xor(v, 4); v += __shfl_xor(v, 8);
            acc[e] = v;               // all 16 lanes hold the full sum
        }
        // softmax + top2 (identical on all lanes of the 16-group)
        float m = acc[0];
        #pragma unroll
        for (int e = 1; e < NE; e++) m = fmaxf(m, acc[e]);
        float s = 0.f;
        #pragma unroll
        for (int e = 0; e < NE; e++) { acc[e] = __expf(acc[e] - m); s += acc[e]; }
        float inv = 1.f / s;
        int i0 = 0; float v0 = acc[0];
        #pragma unroll
        for (int e = 1; e < NE; e++) if (acc[e] > v0) { v0 = acc[e]; i0 = e; }
        int i1 = -1; float v1 = -1.f;
        #pragma unroll
        for (int e = 0; e < NE; e++) if (e != i0 && acc[e] > v1) { v1 = acc[e]; i1 = e; }
        if (kl == 0) {
            ge[2*tok+0] = (unsigned char)i0; gw[2*tok+0] = v0*inv;
            ge[2*tok+1] = (unsigned char)i1; gw[2*tok+1] = v1*inv;
        }
        #pragma unroll
        for (int ee = 0; ee < NE; ee++) {
            int c = __popcll(__ballot(kl == 0 && i0 == ee))
                  + __popcll(__ballot(kl == 0 && i1 == ee));
            if ((tid & 63) == 0 && c) atomicAdd(&lhist[ee], c);
        }
        __syncthreads();
        if (tid < NE) bhist[(size_t)bi*NE + tid] = lhist[tid];
    } else {
        int tz = bi - RTB;
        int zx = tz & 127, zy = tz >> 7;      // 128 64x64 tiles per (tensor,e)
        int tensor = zy >> 3, e = zy & 7;
        const float* src; f16* dst; int R, C;
        if (tensor == 0)      { src = w1; dst = w1t; R = DIM; C = NH; }
        else if (tensor == 1) { src = w3; dst = w3t; R = DIM; C = NH; }
        else                  { src = w2; dst = w2t; R = NH; C = DIM; }
        src += (size_t)e * DIM * NH;
        dst += (size_t)e * DIM * NH;
        int tcols = C >> 6;
        int bx = zx % tcols, by = zx / tcols;
        int r0 = by*64, c0 = bx*64;
        #pragma unroll
        for (int p = 0; p < 4; p++) {
            int r = p*16 + (tid >> 4);
            int c = (tid & 15) << 2;
            float4 v = *(const float4*)&src[(size_t)(r0 + r)*C + c0 + c];
            *(float4*)&smem[r*64 + (c ^ (((r >> 3) & 7) << 2))] = v;
        }
        __syncthreads();
        #pragma unroll
        for (int pass = 0; pass < 2; pass++) {
            int s = pass*256 + tid;
            int h = s >> 3, a = s & 7, d0 = a << 3;
            int hs = h ^ (a << 2);
            f16x8 o;
            #pragma unroll
            for (int j = 0; j < 8; j++)
                o[j] = (f16)smem[(d0 + j)*64 + hs];
            *(f16x8*)&dst[(size_t)(c0 + h)*R + r0 + d0] = o;
        }
    }
}

// ---------------- scatter: atomic-free ranked compaction --------------------
// 64 blocks x 256 assignments. Positions derived deterministically from
// bhist prefix sums: block bi covers router blocks [8bi, 8bi+8), so its
// per-expert base = loffs[e] + sum_{b<8bi} bhist[b][e]. Within the block,
// ranked wave ballots + LDS counters (inter-wave order arbitrary but
// disjoint -> output order-invariant, rows combined via aid).
__global__ __launch_bounds__(256) void scatter_kernel(
    const unsigned char* __restrict__ ge, const float* __restrict__ gw,
    const int* __restrict__ bhist, int* __restrict__ offs,
    int* __restrict__ tok_ids, int* __restrict__ aid,
    float* __restrict__ row_gate)
{
    __shared__ int part_tot[32][NE], part_pre[32][NE];
    __shared__ int s_tot[NE], cur[NE];
    int tid = threadIdx.x;
    int bi = blockIdx.x;

    // cooperative prefix over 512 router-block histograms
    int e = tid & 7, c = tid >> 3;          // c in [0,32)
    int lim = bi*8;
    int tot = 0, pre = 0;
    for (int b = c; b < RTB; b += 32) {
        int v = bhist[(size_t)b*NE + e];
        tot += v;
        if (b < lim) pre += v;
    }
    part_tot[c][e] = tot; part_pre[c][e] = pre;
    __syncthreads();
    if (tid < NE) {
        int t2 = 0, p2 = 0;
        #pragma unroll
        for (int c2 = 0; c2 < 32; c2++) { t2 += part_tot[c2][tid]; p2 += part_pre[c2][tid]; }
        s_tot[tid] = t2;
        part_pre[0][tid] = p2;              // stash full prefix
    }
    __syncthreads();
    int loffs[NE]; int s = 0;
    #pragma unroll
    for (int ee = 0; ee < NE; ee++) { loffs[ee] = s; s += s_tot[ee]; }
    if (bi == 0 && tid == 0) {
        #pragma unroll
        for (int ee = 0; ee < NE; ee++) offs[ee] = loffs[ee];
        offs[NE] = s;
    }
    if (tid < NE) cur[tid] = loffs[tid] + part_pre[0][tid];
    __syncthreads();

    int id = bi*256 + tid;
    int my_e = ge[id];
    float wv = gw[id];
    unsigned long long lt = (1ULL << (tid & 63)) - 1;
    int pos = 0;
    #pragma unroll
    for (int ee = 0; ee < NE; ee++) {
        unsigned long long mk = __ballot(my_e == ee);
        int cnt = __popcll(mk);
        int b = 0;
        if ((tid & 63) == 0 && cnt) b = atomicAdd(&cur[ee], cnt);   // LDS only
        b = __shfl(b, 0);
        if (my_e == ee) pos = b + __popcll(mk & lt);
    }
    tok_ids[pos] = id >> 1;
    aid[pos] = id;
    row_gate[pos] = wv;
}

// ---------------- grouped GEMM tiles ----------------
// BK=64 as two 32-wide sub-tiles, full-drain schedule (proven best: R7).
// e = bi&7: expert == bi mod 8 == XCD under round-robin dispatch -> each
// XCD's L2 holds exactly one expert's weight panels (R6 post-mortem).

// GEMM1: BM=128 x BN=64 dual-B (w1 || w3). 256 B staged per MFMA.
#define BM1 128
#define BN1 64
__global__ __launch_bounds__(256,3) void gemm1_kernel(
    const f16* __restrict__ x16, const int* __restrict__ tok_ids,
    const f16* __restrict__ w1t, const f16* __restrict__ w3t,
    f16* __restrict__ gbuf, const int* __restrict__ offs)
{
    int bi = blockIdx.x;
    int e  = bi & 7;
    int r_ = bi >> 3;
    int nt = r_ & 7;          // NH/BN1 = 8
    int mt = r_ >> 3;
    int off = offs[e];
    int n_e = offs[e+1] - off;
    if (mt*BM1 >= n_e) return;

    __shared__ f16 sA [2][BM1*32];   // 16 KB
    __shared__ f16 sB1[2][BN1*32];   // 8 KB
    __shared__ f16 sB3[2][BN1*32];   // 8 KB
    __shared__ int stok[BM1];

    int tid = threadIdx.x;
    if (tid < BM1) {
        int rloc = mt*BM1 + tid; rloc = rloc < n_e ? rloc : n_e - 1;
        stok[tid] = tok_ids[off + rloc];
    }
    __syncthreads();

    int lane = tid & 63, w = tid >> 6;
    int wrow = (w >> 1)*64, wcol = (w & 1)*32;
    int q = lane >> 4, lm = lane & 15;

    // A staging (DMA, gathered): wave w covers rows [32w, 32w+32) in 2
    // chunks of 16 (proven conflict-free pattern).
    int lr0 = w*32 + (lane >> 2);
    int lr1 = lr0 + 16;
    int gA0 = (lane & 3) ^ ((lr0 >> 1) & 3);
    int gA1 = (lane & 3) ^ ((lr1 >> 1) & 3);
    const f16* pA0 = x16 + (size_t)stok[lr0]*DIM + gA0*8;
    const f16* pA1 = x16 + (size_t)stok[lr1]*DIM + gA1*8;
    const int lofs0 = lr0*32 + ((lane & 3) << 3);
    const int lofs1 = lr1*32 + ((lane & 3) << 3);

    // B staging (DMA): wave w covers rows [16w, 16w+16) of each B.
    int br = w*16 + (lane >> 2);
    int gB = (lane & 3) ^ ((br >> 1) & 3);
    const f16* w1p = w1t + ((size_t)e*NH + nt*BN1)*DIM;
    const f16* w3p = w3t + ((size_t)e*NH + nt*BN1)*DIM;
    const f16* pb1 = w1p + (size_t)br*DIM + gB*8;
    const f16* pb3 = w3p + (size_t)br*DIM + gB*8;
    const int bofs = br*32 + ((lane & 3) << 3);

    f32x4 acc1[4][2], acc3[4][2];
    #pragma unroll
    for (int a = 0; a < 4; a++)
        #pragma unroll
        for (int b = 0; b < 2; b++) {
            acc1[a][b] = (f32x4){0.f,0.f,0.f,0.f};
            acc3[a][b] = (f32x4){0.f,0.f,0.f,0.f};
        }

    for (int k0 = 0; k0 < DIM; k0 += 64) {
        __syncthreads();          // prev-tile FR reads complete
        gl2lds16(pA0 + k0,      &sA [0][lofs0]);
        gl2lds16(pA1 + k0,      &sA [0][lofs1]);
        gl2lds16(pA0 + k0 + 32, &sA [1][lofs0]);
        gl2lds16(pA1 + k0 + 32, &sA [1][lofs1]);
        gl2lds16(pb1 + k0,      &sB1[0][bofs]);
        gl2lds16(pb1 + k0 + 32, &sB1[1][bofs]);
        gl2lds16(pb3 + k0,      &sB3[0][bofs]);
        gl2lds16(pb3 + k0 + 32, &sB3[1][bofs]);
        __syncthreads();          // drains DMA
        #pragma unroll
        for (int ks = 0; ks < 2; ks++) {
            f16x8 aF[4], b1F[2], b3F[2];
            #pragma unroll
            for (int s = 0; s < 4; s++) aF[s] = FR(sA[ks], wrow + s*16 + lm, q);
            #pragma unroll
            for (int c = 0; c < 2; c++) {
                b1F[c] = FR(sB1[ks], wcol + c*16 + lm, q);
                b3F[c] = FR(sB3[ks], wcol + c*16 + lm, q);
            }
            #pragma unroll
            for (int sr = 0; sr < 4; sr++)
                #pragma unroll
                for (int sc = 0; sc < 2; sc++) {
                    acc1[sr][sc] = __builtin_amdgcn_mfma_f32_16x16x32_f16(aF[sr], b1F[sc], acc1[sr][sc], 0, 0, 0);
                    acc3[sr][sc] = __builtin_amdgcn_mfma_f32_16x16x32_f16(aF[sr], b3F[sc], acc3[sr][sc], 0, 0, 0);
                }
        }
    }
    // epilogue: silu(h1)*h3 -> f16 gbuf.  C/D: col=lane&15, row=(lane>>4)*4+reg
    #pragma unroll
    for (int sr = 0; sr < 4; sr++) {
        #pragma unroll
        for (int reg = 0; reg < 4; reg++) {
            int row = mt*BM1 + wrow + sr*16 + q*4 + reg;
            if (row < n_e) {
                #pragma unroll
                for (int sc = 0; sc < 2; sc++) {
                    int col = nt*BN1 + wcol + sc*16 + lm;
                    float h1 = acc1[sr][sc][reg];
                    float h3 = acc3[sr][sc][reg];
                    float gv = h1 / (1.f + __expf(-h1)) * h3;
                    gbuf[(size_t)(off + row)*NH + col] = (f16)gv;
                }
            }
        }
    }
}

// GEMM2: ybuf[aid[row]] = gate * (G @ W2). Full DMA staging, BK=64, 8 iters.
#define BM 128
#define BN 128
__global__ __launch_bounds__(256,3) void gemm2_kernel(
    const f16* __restrict__ gbuf, const f16* __restrict__ w2t,
    const int* __restrict__ offs, const int* __restrict__ aid,
    const float* __restrict__ row_gate, f16* __restrict__ ybuf)
{
    int bi = blockIdx.x;
    int e  = bi & 7;
    int r_ = bi >> 3;
    int nt = r_ & 7;          // DIM/BN = 8
    int mt = r_ >> 3;
    int off = offs[e];
    int n_e = offs[e+1] - off;
    if (mt*BM >= n_e) return;

    __shared__ f16 sA[2][BM*32];   // 16 KB
    __shared__ f16 sB[2][BN*32];   // 16 KB
    __shared__ int said[BM];
    __shared__ float sgate[BM];

    int tid = threadIdx.x;
    if (tid < BM) {
        int rloc = mt*BM + tid;
        if (rloc < n_e) { said[tid] = aid[off + rloc]; sgate[tid] = row_gate[off + rloc]; }
        else            { said[tid] = 0; sgate[tid] = 0.f; }
    }

    int lane = tid & 63, w = tid >> 6;
    int wrow = (w >> 1)*64, wcol = (w & 1)*64;
    int q = lane >> 4, lm = lane & 15;

    int lr0 = w*32 + (lane >> 2);
    int lr1 = lr0 + 16;
    int g0 = (lane & 3) ^ ((lr0 >> 1) & 3);
    int g1 = (lane & 3) ^ ((lr1 >> 1) & 3);
    int ga0 = mt*BM + lr0; ga0 = ga0 < n_e ? ga0 : n_e - 1;
    int ga1 = mt*BM + lr1; ga1 = ga1 < n_e ? ga1 : n_e - 1;
    const f16* pA0 = gbuf + (size_t)(off + ga0)*NH + g0*8;
    const f16* pA1 = gbuf + (size_t)(off + ga1)*NH + g1*8;
    const f16* w2p = w2t + ((size_t)e*DIM + nt*BN)*NH;
    const f16* pB0 = w2p + (size_t)lr0*NH + g0*8;
    const f16* pB1 = w2p + (size_t)lr1*NH + g1*8;
    const int lofs0 = lr0*32 + ((lane & 3) << 3);
    const int lofs1 = lr1*32 + ((lane & 3) << 3);

    f32x4 acc[4][4];
    #pragma unroll
    for (int a = 0; a < 4; a++)
        #pragma unroll
        for (int b = 0; b < 4; b++) acc[a][b] = (f32x4){0.f,0.f,0.f,0.f};

    __syncthreads();   // covers said/sgate writes

    for (int k0 = 0; k0 < NH; k0 += 64) {
        gl2lds16(pA0 + k0,      &sA[0][lofs0]);
        gl2lds16(pA1 + k0,      &sA[0][lofs1]);
        gl2lds16(pA0 + k0 + 32, &sA[1][lofs0]);
        gl2lds16(pA1 + k0 + 32, &sA[1][lofs1]);
        gl2lds16(pB0 + k0,      &sB[0][lofs0]);
        gl2lds16(pB1 + k0,      &sB[0][lofs1]);
        gl2lds16(pB0 + k0 + 32, &sB[1][lofs0]);
        gl2lds16(pB1 + k0 + 32, &sB[1][lofs1]);
        __syncthreads();   // drains vmcnt
        #pragma unroll
        for (int ks = 0; ks < 2; ks++) {
            f16x8 aF[4], bF[4];
            #pragma unroll
            for (int s = 0; s < 4; s++) {
                aF[s] = FR(sA[ks], wrow + s*16 + lm, q);
                bF[s] = FR(sB[ks], wcol + s*16 + lm, q);
            }
            #pragma unroll
            for (int sr = 0; sr < 4; sr++)
                #pragma unroll
                for (int sc = 0; sc < 4; sc++)
                    acc[sr][sc] = __builtin_amdgcn_mfma_f32_16x16x32_f16(aF[sr], bF[sc], acc[sr][sc], 0, 0, 0);
        }
        __syncthreads();   // reads done before next iter's DMA
    }
    #pragma unroll
    for (int sr = 0; sr < 4; sr++) {
        #pragma unroll
        for (int reg = 0; reg < 4; reg++) {
            int lrow = wrow + sr*16 + q*4 + reg;
            if (mt*BM + lrow < n_e) {
                int id = said[lrow];
                float wgt = sgate[lrow];
                #pragma unroll
                for (int sc = 0; sc < 4; sc++) {
                    int col = nt*BN + wcol + sc*16 + lm;
                    ybuf[(size_t)id*DIM + col] = (f16)(wgt * acc[sr][sc][reg]);
                }
            }
        }
    }
}

// ---------------- combine: out[t] = ybuf[2t] + ybuf[2t+1] ----------------
__global__ __launch_bounds__(256) void combine_kernel(
    const f16* __restrict__ ybuf, float* __restrict__ out)
{
    int gid = blockIdx.x*256 + threadIdx.x;
    int t = gid >> 7;
    int c = (gid & 127) << 3;
    f16x8 y0 = *(const f16x8*)(ybuf + ((size_t)2*t)*DIM + c);
    f16x8 y1 = *(const f16x8*)(ybuf + ((size_t)2*t+1)*DIM + c);
    float* op = out + (size_t)t*DIM + c;
    float4 o0 = { (float)y0[0] + (float)y1[0], (float)y0[1] + (float)y1[1],
                  (float)y0[2] + (float)y1[2], (float)y0[3] + (float)y1[3] };
    float4 o1 = { (float)y0[4] + (float)y1[4], (float)y0[5] + (float)y1[5],
                  (float)y0[6] + (float)y1[6], (float)y0[7] + (float)y1[7] };
    *(float4*)op = o0;
    *(float4*)(op + 4) = o1;
}

extern "C" void kernel_launch(void* const* d_in, const int* in_sizes, int n_in,
                              void* d_out, int out_size, void* d_ws, size_t ws_size,
                              hipStream_t stream)
{
    const float* x  = (const float*)d_in[0];
    const float* wr = (const float*)d_in[1];
    const float* w1 = (const float*)d_in[2];
    const float* w2 = (const float*)d_in[3];
    const float* w3 = (const float*)d_in[4];
    float* out = (float*)d_out;

    char* ws = (char*)d_ws;
    f16* ybuf    = (f16*)ws;        ws += (size_t)NROWS*DIM*sizeof(f16);   // 32 MiB (writer: gemm2)
    f16* w1t     = (f16*)ws;        ws += (size_t)NE*NH*DIM*sizeof(f16);   // 8 MiB (writer: prep)
    f16* w3t     = (f16*)ws;        ws += (size_t)NE*NH*DIM*sizeof(f16);   // 8 MiB (writer: prep)
    f16* w2t     = (f16*)ws;        ws += (size_t)NE*DIM*NH*sizeof(f16);   // 8 MiB (writer: prep)
    f16* gbuf    = (f16*)ws;        ws += (size_t)NROWS*NH*sizeof(f16);    // 16 MiB (writer: gemm1)
    int* tok_ids = (int*)ws;        ws += (size_t)NROWS*4;                 // (writer: scatter)
    int* aid     = (int*)ws;        ws += (size_t)NROWS*4;
    float* row_gate = (float*)ws;   ws += (size_t)NROWS*4;
    int* offs    = (int*)ws;        ws += 64;
    unsigned char* ge = (unsigned char*)ws; ws += (size_t)NROWS;           // (writer: prep)
    float* gw    = (float*)ws;      ws += (size_t)NROWS*4;
    int* bhist   = (int*)ws;        ws += (size_t)RTB*NE*4;                // 16 KiB (writer: prep)
    if (ws_size < (size_t)(ws - (char*)d_ws)) return;  // ~72.3 MB needed

    // x16 aliases ybuf: prep writes it, gemm1 reads it, then gemm2 overwrites
    // the region with ybuf (x16 dead by then). 16 MiB, zero workspace growth.
    f16* x16 = ybuf;

    prep_kernel<<<RTB + 3072, 256, 0, stream>>>(x, wr, w1, w3, w2,
                                                x16, w1t, w3t, w2t,
                                                ge, gw, bhist);
    scatter_kernel<<<NROWS/256, 256, 0, stream>>>(ge, gw, bhist, offs,
                                                  tok_ids, aid, row_gate);
    gemm1_kernel<<<4096, 256, 0, stream>>>(x16, tok_ids, w1t, w3t, gbuf, offs);
    gemm2_kernel<<<8192, 256, 0, stream>>>(gbuf, w2t, offs, aid, row_gate, ybuf);
    combine_kernel<<<(NT*(DIM/8))/256, 256, 0, stream>>>(ybuf, out);
}